// Round 5
// baseline (88.671 us; speedup 1.0000x reference)
//
#include <hip/hip_runtime.h>
#include <cstdint>
#include <cstddef>

#define BB 16
#define AA 8400
#define CC 80
#define MM 32
#define TOPK 13
#define NCH 16
#define CHSZ (AA / NCH)   // 525

// Shared CIoU (clipped) so every use site has the identical formula.
__device__ __forceinline__ float ciou_clip(
    float gx1, float gy1, float gx2, float gy2, float at1,
    float4 pb, float w2, float h2, float at2)
{
  const float w1 = gx2 - gx1, h1 = gy2 - gy1 + 1e-7f;
  const float iw = fmaxf(fminf(gx2, pb.z) - fmaxf(gx1, pb.x), 0.f);
  const float ih = fmaxf(fminf(gy2, pb.w) - fmaxf(gy1, pb.y), 0.f);
  const float inter = iw * ih;
  const float uni = w1*h1 + w2*h2 - inter + 1e-7f;
  const float iou = inter / uni;
  const float cw = fmaxf(gx2, pb.z) - fminf(gx1, pb.x);
  const float ch = fmaxf(gy2, pb.w) - fminf(gy1, pb.y);
  const float c2 = cw*cw + ch*ch + 1e-7f;
  const float rx = pb.x + pb.z - gx1 - gx2;
  const float ry = pb.y + pb.w - gy1 - gy2;
  const float rho2 = (rx*rx + ry*ry) * 0.25f;
  const float dv = at2 - at1;
  const float v = 0.4052847345693511f * dv * dv;
  const float alpha = v / (v - iou + (1.f + 1e-7f));
  return fmaxf(iou - (rho2 / c2 + v * alpha), 0.f);
}

// ---------------------------------------------------------------------------
// K0: score transpose. Thread (b,a) reads its OWN 320B pred_cls row at the 32
// gt labels (label-sorted for line-burst locality) and writes scores[b][m][a]
// coalesced. Also: at2 (atanf of pred box) hoist, claim/pos_* zero-init.
// ---------------------------------------------------------------------------
__global__ __launch_bounds__(256) void k_scores(
    const float* __restrict__ pred_cls, const float* __restrict__ pred_bbox,
    const int* __restrict__ gt_cls,
    float* __restrict__ scores, float* __restrict__ at2_buf,
    unsigned int* __restrict__ claim,
    unsigned int* __restrict__ pos_align, unsigned int* __restrict__ pos_ovl)
{
  const int b = blockIdx.y;
  __shared__ int s_lbl[MM], s_ord[MM];
  if (threadIdx.x < MM) s_lbl[threadIdx.x] = gt_cls[b*MM + threadIdx.x];
  __syncthreads();
  if (threadIdx.x < MM) {
    // stable rank-sort by label (block-uniform result)
    const int li = s_lbl[threadIdx.x];
    int rank = 0;
    #pragma unroll
    for (int j = 0; j < MM; ++j) {
      const int lj = s_lbl[j];
      rank += (lj < li) || (lj == li && j < (int)threadIdx.x);
    }
    s_ord[rank] = threadIdx.x;
    if (blockIdx.x == 0) {                 // zero pos_* (4 KB total)
      pos_align[b*MM + threadIdx.x] = 0u;
      pos_ovl[b*MM + threadIdx.x]   = 0u;
    }
  }
  __syncthreads();
  const int a = blockIdx.x*256 + threadIdx.x;
  if (a >= AA) return;
  claim[b*AA + a] = 0u;
  const float4 pb = reinterpret_cast<const float4*>(pred_bbox)[b*AA + a];
  at2_buf[b*AA + a] = atanf((pb.z - pb.x) / (pb.w - pb.y + 1e-7f));
  const float* row = pred_cls + ((size_t)(b*AA + a)) * CC;
  float* sc = scores + (size_t)b*MM*AA + a;
  #pragma unroll 8
  for (int k = 0; k < MM; ++k) {
    const int m = s_ord[k];                // label-ascending access order
    sc[(size_t)m*AA] = row[s_lbl[m]];      // store coalesced across lanes
  }
}

// ---------------------------------------------------------------------------
// K1: per-(b,m,chunk) align on the fly (coalesced scores read) + exact
// top-13 of the 525-anchor chunk in registers.
// Tie semantics: (val desc, idx asc) — matches jax.lax.top_k.
// ---------------------------------------------------------------------------
__global__ __launch_bounds__(64) void k_topk_p1(
    const float* __restrict__ scores, const float* __restrict__ pred_bbox,
    const float* __restrict__ anchors, const float* __restrict__ at2_buf,
    const float* __restrict__ gt_bbox, const float* __restrict__ mask_gt,
    float* __restrict__ pvals, int* __restrict__ pidx)
{
  const int ch = blockIdx.x, m = blockIdx.y, b = blockIdx.z;
  const int lane = threadIdx.x;
  if (mask_gt[b*MM + m] <= 0.f) return;    // masked gt: contributes nothing

  const float4 gb = reinterpret_cast<const float4*>(gt_bbox)[b*MM + m];
  const float at1 = atanf((gb.z - gb.x) / (gb.w - gb.y + 1e-7f));
  const float* srow = scores + ((size_t)(b*MM + m)) * AA;
  const float4* pbase = reinterpret_cast<const float4*>(pred_bbox) + (size_t)b*AA;
  const float* arow = at2_buf + (size_t)b*AA;

  // per-lane top-13, sorted desc, ties: earlier (lower) index stays ahead
  float v[TOPK]; int id[TOPK];
  #pragma unroll
  for (int i = 0; i < TOPK; ++i) { v[i] = -1.f; id[i] = 0x7fffffff; }

  const int a0 = ch * CHSZ;
  for (int a = a0 + lane; a < a0 + CHSZ; a += 64) {
    const float2 xy = reinterpret_cast<const float2*>(anchors)[a];
    const float mind = fminf(fminf(xy.x - gb.x, xy.y - gb.y),
                             fminf(gb.z - xy.x, gb.w - xy.y));
    float val = 0.f;
    if (mind > 1e-9f) {
      const float4 pb = pbase[a];
      const float w2 = pb.z - pb.x, h2 = pb.w - pb.y + 1e-7f;
      const float ov = ciou_clip(gb.x, gb.y, gb.z, gb.w, at1, pb, w2, h2, arow[a]);
      const float o2 = ov * ov;
      val = srow[a] * (o2 * o2 * o2);      // score * ov^6 (monotone == pow)
    }
    if (val > v[TOPK-1]) {      // equal loses (higher index) -> skip
      #pragma unroll
      for (int i = TOPK-1; i >= 1; --i) {   // static-index shift network
        const bool ci = val > v[i];
        const bool cp = val > v[i-1];
        if (ci) {
          if (cp) { v[i] = v[i-1]; id[i] = id[i-1]; }
          else    { v[i] = val;    id[i] = a; }
        }
      }
      if (val > v[0]) { v[0] = val; id[0] = a; }
    }
  }

  float* pv = pvals + (((size_t)(b*MM + m))*NCH + ch) * TOPK;
  int*   pi = pidx  + (((size_t)(b*MM + m))*NCH + ch) * TOPK;
  for (int r = 0; r < TOPK; ++r) {
    float bv = v[0]; int bi = id[0];
    #pragma unroll
    for (int off = 32; off; off >>= 1) {
      const float ovv = __shfl_xor(bv, off);
      const int   oii = __shfl_xor(bi, off);
      if (ovv > bv || (ovv == bv && oii < bi)) { bv = ovv; bi = oii; }
    }
    if (v[0] == bv && id[0] == bi) {        // unique winner pops its head
      #pragma unroll
      for (int i = 0; i < TOPK-1; ++i) { v[i] = v[i+1]; id[i] = id[i+1]; }
      v[TOPK-1] = -1.f; id[TOPK-1] = 0x7fffffff;
    }
    if (lane == 0) { pv[r] = bv; pi[r] = bi; }
  }
}

// ---------------------------------------------------------------------------
// K2: per-(b,m) merge of 16x13 = 208 candidates -> global top-13, then
// mask_in_gts check + claim-bit atomicOr. One wave per (b,m).
// ---------------------------------------------------------------------------
__global__ __launch_bounds__(64) void k_topk_p2(
    const float* __restrict__ pvals, const int* __restrict__ pidx,
    const float* __restrict__ anchors, const float* __restrict__ gt_bbox,
    const float* __restrict__ mask_gt, unsigned int* __restrict__ claim)
{
  const int m = blockIdx.x, b = blockIdx.y;
  if (mask_gt[b*MM + m] <= 0.f) return;
  const int lane = threadIdx.x;
  const float* pv = pvals + ((size_t)(b*MM + m)) * NCH * TOPK;
  const int*   pi = pidx  + ((size_t)(b*MM + m)) * NCH * TOPK;
  const int NC = NCH * TOPK;   // 208

  // 4 static slots per lane (rule #20: never dynamic-index these)
  float v0=-1.f, v1=-1.f, v2=-1.f, v3=-1.f;
  int   i0=0x7fffffff, i1=0x7fffffff, i2=0x7fffffff, i3=0x7fffffff;
  { int j;
    j = lane;        if (j < NC) { v0 = pv[j]; i0 = pi[j]; }
    j = lane + 64;   if (j < NC) { v1 = pv[j]; i1 = pi[j]; }
    j = lane + 128;  if (j < NC) { v2 = pv[j]; i2 = pi[j]; }
    j = lane + 192;  if (j < NC) { v3 = pv[j]; i3 = pi[j]; }
  }

  const float4 gb = reinterpret_cast<const float4*>(gt_bbox)[b*MM + m];
  const unsigned int bit = 1u << m;

  for (int r = 0; r < TOPK; ++r) {
    float bv = v0; int bi = i0; int bs = 0;
    if (v1 > bv || (v1 == bv && i1 < bi)) { bv = v1; bi = i1; bs = 1; }
    if (v2 > bv || (v2 == bv && i2 < bi)) { bv = v2; bi = i2; bs = 2; }
    if (v3 > bv || (v3 == bv && i3 < bi)) { bv = v3; bi = i3; bs = 3; }
    const float myv = bv; const int myi = bi;
    #pragma unroll
    for (int off = 32; off; off >>= 1) {
      const float ovv = __shfl_xor(bv, off);
      const int   oii = __shfl_xor(bi, off);
      if (ovv > bv || (ovv == bv && oii < bi)) { bv = ovv; bi = oii; }
    }
    if (myv == bv && myi == bi) {           // winner lane clears its slot
      if (bs == 0) { v0 = -1.f; i0 = 0x7fffffff; }
      if (bs == 1) { v1 = -1.f; i1 = 0x7fffffff; }
      if (bs == 2) { v2 = -1.f; i2 = 0x7fffffff; }
      if (bs == 3) { v3 = -1.f; i3 = 0x7fffffff; }
    }
    if (lane == 0 && bi < AA) {
      const float2 xy = reinterpret_cast<const float2*>(anchors)[bi];
      const float mind = fminf(fminf(xy.x - gb.x, xy.y - gb.y),
                               fminf(gb.z - xy.x, gb.w - xy.y));
      if (mind > 1e-9f) atomicOr(&claim[b*AA + bi], bit);
    }
  }
}

// ---------------------------------------------------------------------------
// K3: per-anchor resolution with sparse CIoU recompute. fg==1 -> claiming m;
// fg>1 -> first-max argmax_m of masked overlaps (recomputed). Writes
// target_bbox + fg_mask + anchor_m/al; atomicMax pos_align/pos_ovl.
// ---------------------------------------------------------------------------
__global__ __launch_bounds__(256) void k_resolve(
    const float* __restrict__ pred_cls, const float* __restrict__ pred_bbox,
    const float* __restrict__ anchors, const int* __restrict__ gt_cls,
    const float* __restrict__ gt_bbox, const float* __restrict__ mask_gt,
    const unsigned int* __restrict__ claim,
    float* __restrict__ out_bbox, float* __restrict__ out_fg,
    int* __restrict__ anchor_m, float* __restrict__ anchor_al,
    unsigned int* __restrict__ pos_align, unsigned int* __restrict__ pos_ovl)
{
  const int b = blockIdx.y;
  __shared__ float s_x1[MM], s_y1[MM], s_x2[MM], s_y2[MM], s_at[MM], s_mgt[MM];
  __shared__ int s_lbl[MM];
  if (threadIdx.x < MM) {
    int m = threadIdx.x;
    float4 g = reinterpret_cast<const float4*>(gt_bbox)[b*MM + m];
    s_x1[m] = g.x; s_y1[m] = g.y; s_x2[m] = g.z; s_y2[m] = g.w;
    s_at[m] = atanf((g.z - g.x) / (g.w - g.y + 1e-7f));
    s_lbl[m] = gt_cls[b*MM + m];
    s_mgt[m] = mask_gt[b*MM + m];
  }
  __syncthreads();
  const int a = blockIdx.x*256 + threadIdx.x;
  if (a >= AA) return;
  const unsigned int cb = claim[b*AA + a];
  const int fg = __popc(cb);
  int asg = -1; float bestov = 0.f;
  if (fg > 0) {
    const float4 pb = reinterpret_cast<const float4*>(pred_bbox)[b*AA + a];
    const float2 xy = reinterpret_cast<const float2*>(anchors)[a];
    const float w2 = pb.z - pb.x, h2 = pb.w - pb.y + 1e-7f;
    const float at2 = atanf(w2 / h2);
    if (fg == 1) {
      asg = __ffs(cb) - 1;   // claimed => in-gts && mask_gt>0 already hold
      bestov = ciou_clip(s_x1[asg], s_y1[asg], s_x2[asg], s_y2[asg], s_at[asg],
                         pb, w2, h2, at2);
    } else {
      // is_max: first argmax over ALL m of masked overlaps
      float best = -1.f; int bm = 0;
      for (int m = 0; m < MM; ++m) {
        float ov = 0.f;
        const float mind = fminf(fminf(xy.x - s_x1[m], xy.y - s_y1[m]),
                                 fminf(s_x2[m] - xy.x, s_y2[m] - xy.y));
        if (mind > 1e-9f && s_mgt[m] > 0.f)
          ov = ciou_clip(s_x1[m], s_y1[m], s_x2[m], s_y2[m], s_at[m],
                         pb, w2, h2, at2);
        if (ov > best) { best = ov; bm = m; }   // strict > => first max
      }
      asg = bm; bestov = best;
    }
  }
  const int tgt = (asg >= 0) ? asg : 0;   // argmax of all-zero column = 0
  float4 tb; tb.x = s_x1[tgt]; tb.y = s_y1[tgt]; tb.z = s_x2[tgt]; tb.w = s_y2[tgt];
  reinterpret_cast<float4*>(out_bbox)[b*AA + a] = tb;
  out_fg[b*AA + a] = (asg >= 0) ? 1.f : 0.f;
  anchor_m[b*AA + a] = asg;
  float av = 0.f;
  if (asg >= 0) {
    const float o2 = bestov * bestov;
    av = pred_cls[(size_t)(b*AA + a)*CC + s_lbl[asg]] * (o2 * o2 * o2);
    atomicMax(&pos_align[b*MM + asg], __float_as_uint(av));    // >=0 floats
    atomicMax(&pos_ovl[b*MM + asg], __float_as_uint(bestov));
  }
  anchor_al[b*AA + a] = av;
}

// ---------------------------------------------------------------------------
// K4: target_cls (B,A,C) float4-coalesced: norm at the label slot, else 0.
// ---------------------------------------------------------------------------
__global__ __launch_bounds__(256) void k_cls(
    const int* __restrict__ anchor_m, const float* __restrict__ anchor_al,
    const unsigned int* __restrict__ pos_align, const unsigned int* __restrict__ pos_ovl,
    const int* __restrict__ gt_cls, float* __restrict__ out_cls)
{
  const int tid = blockIdx.x*256 + threadIdx.x;
  if (tid >= BB*AA*(CC/4)) return;
  const int q  = tid % (CC/4);
  const int ba = tid / (CC/4);
  const int b  = ba / AA;
  const int m  = anchor_m[ba];
  float4 o = make_float4(0.f, 0.f, 0.f, 0.f);
  if (m >= 0) {
    const float pa = __uint_as_float(pos_align[b*MM + m]);
    const float po = __uint_as_float(pos_ovl[b*MM + m]);
    const float norm = anchor_al[ba] * po / (pa + 1e-9f);
    const int lbl = gt_cls[b*MM + m];
    const int c0 = q * 4;
    if (lbl == c0    ) o.x = norm;
    if (lbl == c0 + 1) o.y = norm;
    if (lbl == c0 + 2) o.z = norm;
    if (lbl == c0 + 3) o.w = norm;
  }
  reinterpret_cast<float4*>(out_cls)[tid] = o;
}

// ---------------------------------------------------------------------------
extern "C" void kernel_launch(void* const* d_in, const int* in_sizes, int n_in,
                              void* d_out, int out_size, void* d_ws, size_t ws_size,
                              hipStream_t stream)
{
  const float* pred_cls  = (const float*)d_in[0];
  const float* pred_bbox = (const float*)d_in[1];
  const float* anchors   = (const float*)d_in[2];
  const int*   gt_cls    = (const int*)  d_in[3];
  const float* gt_bbox   = (const float*)d_in[4];
  const float* mask_gt   = (const float*)d_in[5];

  // ws layout:
  //   claim      : B*A u32          @ 0          (537600 B)
  //   pos_align  : B*M u32(float)   @ 537600     (2048 B)
  //   pos_ovl    : B*M u32(float)   @ 539648     (2048 B)
  //   anchor_m   : B*A i32          @ 541696     (537600 B)
  //   anchor_al  : B*A f32          @ 1079296    (537600 B)
  //   pvals      : B*M*NCH*13 f32   @ 1616896    (425984 B)
  //   pidx       : B*M*NCH*13 i32   @ 2042880    (425984 B)
  //   at2        : B*A f32          @ 2468864    (537600 B)
  //   scores     : B*M*A f32        @ 3006464    (17203200 B)
  // total 20209664 B (~19.3 MB)
  char* ws = (char*)d_ws;
  unsigned int* claim     = (unsigned int*)(ws);
  unsigned int* pos_align = (unsigned int*)(ws + 537600);
  unsigned int* pos_ovl   = (unsigned int*)(ws + 539648);
  int*   anchor_m  = (int*)  (ws + 541696);
  float* anchor_al = (float*)(ws + 1079296);
  float* pvals     = (float*)(ws + 1616896);
  int*   pidx      = (int*)  (ws + 2042880);
  float* at2_buf   = (float*)(ws + 2468864);
  float* scores    = (float*)(ws + 3006464);

  float* out_cls  = (float*)d_out;
  float* out_bbox = out_cls + (size_t)BB*AA*CC;
  float* out_fg   = out_bbox + (size_t)BB*AA*4;

  k_scores<<<dim3((AA + 255)/256, BB), 256, 0, stream>>>(
      pred_cls, pred_bbox, gt_cls, scores, at2_buf, claim, pos_align, pos_ovl);
  k_topk_p1<<<dim3(NCH, MM, BB), 64, 0, stream>>>(
      scores, pred_bbox, anchors, at2_buf, gt_bbox, mask_gt, pvals, pidx);
  k_topk_p2<<<dim3(MM, BB), 64, 0, stream>>>(
      pvals, pidx, anchors, gt_bbox, mask_gt, claim);
  k_resolve<<<dim3((AA + 255)/256, BB), 256, 0, stream>>>(
      pred_cls, pred_bbox, anchors, gt_cls, gt_bbox, mask_gt, claim,
      out_bbox, out_fg, anchor_m, anchor_al, pos_align, pos_ovl);
  k_cls<<<(BB*AA*(CC/4) + 255)/256, 256, 0, stream>>>(
      anchor_m, anchor_al, pos_align, pos_ovl, gt_cls, out_cls);
}

// Round 6
// 75.703 us; speedup vs baseline: 1.1713x; 1.1713x over previous
//
#include <hip/hip_runtime.h>
#include <cstdint>
#include <cstddef>

#define BB 16
#define AA 8400
#define CC 80
#define MM 32
#define TOPK 13
#define NCH 8
#define CHSZ (AA / NCH)   // 1050
#define WPB 4             // waves (chunks) per 256-thread block

// Shared CIoU (clipped) so every use site has the identical formula.
__device__ __forceinline__ float ciou_clip(
    float gx1, float gy1, float gx2, float gy2, float at1,
    float4 pb, float w2, float h2, float at2)
{
  const float w1 = gx2 - gx1, h1 = gy2 - gy1 + 1e-7f;
  const float iw = fmaxf(fminf(gx2, pb.z) - fmaxf(gx1, pb.x), 0.f);
  const float ih = fmaxf(fminf(gy2, pb.w) - fmaxf(gy1, pb.y), 0.f);
  const float inter = iw * ih;
  const float uni = w1*h1 + w2*h2 - inter + 1e-7f;
  const float iou = inter / uni;
  const float cw = fmaxf(gx2, pb.z) - fminf(gx1, pb.x);
  const float ch = fmaxf(gy2, pb.w) - fminf(gy1, pb.y);
  const float c2 = cw*cw + ch*ch + 1e-7f;
  const float rx = pb.x + pb.z - gx1 - gx2;
  const float ry = pb.y + pb.w - gy1 - gy2;
  const float rho2 = (rx*rx + ry*ry) * 0.25f;
  const float dv = at2 - at1;
  const float v = 0.4052847345693511f * dv * dv;
  const float alpha = v / (v - iou + (1.f + 1e-7f));
  return fmaxf(iou - (rho2 / c2 + v * alpha), 0.f);
}

// ---------------------------------------------------------------------------
// K1 (fused): block = (chunk-quad, m, b), 4 waves; each WAVE owns one
// 1050-anchor chunk: computes align on the fly, keeps exact top-13 in
// registers (batch-4 unrolled scan -> 4 independent load chains per batch),
// then 13-round butterfly merge -> pvals/pidx. Zero-init duties included.
// Tie semantics: (val desc, idx asc) — matches jax.lax.top_k.
// ---------------------------------------------------------------------------
__global__ __launch_bounds__(256) void k_fused_topk(
    const float* __restrict__ pred_cls, const float* __restrict__ pred_bbox,
    const float* __restrict__ anchors, const int* __restrict__ gt_cls,
    const float* __restrict__ gt_bbox, const float* __restrict__ mask_gt,
    float* __restrict__ pvals, int* __restrict__ pidx,
    unsigned int* __restrict__ claim,
    unsigned int* __restrict__ pos_align, unsigned int* __restrict__ pos_ovl)
{
  const int wave = threadIdx.x >> 6;     // 0..3
  const int lane = threadIdx.x & 63;
  const int chq  = blockIdx.x;           // 0..NCH/WPB-1
  const int m = blockIdx.y, b = blockIdx.z;
  const int ch = chq*WPB + wave;

  if (m == 0) {                          // zero-init duty (replaces memset)
    const int base = b*AA + chq*(WPB*CHSZ);
    for (int i = threadIdx.x; i < WPB*CHSZ; i += 256) claim[base + i] = 0u;
    if (chq == 0 && threadIdx.x < MM) {
      pos_align[b*MM + threadIdx.x] = 0u;
      pos_ovl[b*MM + threadIdx.x]   = 0u;
    }
  }
  if (mask_gt[b*MM + m] <= 0.f) return;  // masked gt: contributes nothing

  const float4 gb = reinterpret_cast<const float4*>(gt_bbox)[b*MM + m];
  const float at1 = atanf((gb.z - gb.x) / (gb.w - gb.y + 1e-7f));
  const int lbl = gt_cls[b*MM + m];
  const float*  clsbase = pred_cls + (size_t)b*AA*CC;
  const float4* pbase   = reinterpret_cast<const float4*>(pred_bbox) + (size_t)b*AA;
  const float2* axy     = reinterpret_cast<const float2*>(anchors);

  // per-lane top-13, sorted desc, ties: earlier (lower) index stays ahead
  float v[TOPK]; int id[TOPK];
  #pragma unroll
  for (int i = 0; i < TOPK; ++i) { v[i] = -1.f; id[i] = 0x7fffffff; }

  const int a0 = ch * CHSZ;

  // 16 full strides in 4 batches of 4 (all-static indices)
  #pragma unroll
  for (int jb = 0; jb < 4; ++jb) {
    float val_[4]; int a_[4];
    #pragma unroll
    for (int t = 0; t < 4; ++t) {
      const int a = a0 + lane + (jb*4 + t)*64;   // < a0+1024 <= row end
      a_[t] = a;
      const float2 xy = axy[a];
      const float4 pb = pbase[a];
      const float mind = fminf(fminf(xy.x - gb.x, xy.y - gb.y),
                               fminf(gb.z - xy.x, gb.w - xy.y));
      float val = 0.f;
      if (mind > 1e-9f) {
        const float w2 = pb.z - pb.x, h2 = pb.w - pb.y + 1e-7f;
        const float at2 = atanf(w2 / h2);
        const float ov = ciou_clip(gb.x, gb.y, gb.z, gb.w, at1, pb, w2, h2, at2);
        const float o2 = ov * ov;
        val = clsbase[(size_t)a*CC + lbl] * (o2 * o2 * o2);  // score * ov^6
      }
      val_[t] = val;
    }
    #pragma unroll
    for (int t = 0; t < 4; ++t) {
      const float val = val_[t];
      if (val > v[TOPK-1]) {    // equal loses (higher index) -> skip
        #pragma unroll
        for (int i = TOPK-1; i >= 1; --i) {   // static-index shift network
          const bool ci = val > v[i];
          const bool cp = val > v[i-1];
          if (ci) {
            if (cp) { v[i] = v[i-1]; id[i] = id[i-1]; }
            else    { v[i] = val;    id[i] = a_[t]; }
          }
        }
        if (val > v[0]) { v[0] = val; id[0] = a_[t]; }
      }
    }
  }
  // tail stride (elements 1024..1049 of the chunk): lanes < 26 active
  {
    const int a = a0 + 1024 + lane;
    const int ac = (a < AA) ? a : (AA - 1);    // clamp loads in-bounds
    const float2 xy = axy[ac];
    const float4 pb = pbase[ac];
    const float mind = fminf(fminf(xy.x - gb.x, xy.y - gb.y),
                             fminf(gb.z - xy.x, gb.w - xy.y));
    float val = 0.f;
    if (mind > 1e-9f) {
      const float w2 = pb.z - pb.x, h2 = pb.w - pb.y + 1e-7f;
      const float at2 = atanf(w2 / h2);
      const float ov = ciou_clip(gb.x, gb.y, gb.z, gb.w, at1, pb, w2, h2, at2);
      const float o2 = ov * ov;
      val = clsbase[(size_t)ac*CC + lbl] * (o2 * o2 * o2);
    }
    if (a < a0 + CHSZ && val > v[TOPK-1]) {
      #pragma unroll
      for (int i = TOPK-1; i >= 1; --i) {
        const bool ci = val > v[i];
        const bool cp = val > v[i-1];
        if (ci) {
          if (cp) { v[i] = v[i-1]; id[i] = id[i-1]; }
          else    { v[i] = val;    id[i] = a; }
        }
      }
      if (val > v[0]) { v[0] = val; id[0] = a; }
    }
  }

  // wave-level 13-round extraction (val desc, idx asc)
  float* pv = pvals + (((size_t)(b*MM + m))*NCH + ch) * TOPK;
  int*   pi = pidx  + (((size_t)(b*MM + m))*NCH + ch) * TOPK;
  for (int r = 0; r < TOPK; ++r) {
    float bv = v[0]; int bi = id[0];
    #pragma unroll
    for (int off = 32; off; off >>= 1) {
      const float ovv = __shfl_xor(bv, off);
      const int   oii = __shfl_xor(bi, off);
      if (ovv > bv || (ovv == bv && oii < bi)) { bv = ovv; bi = oii; }
    }
    if (v[0] == bv && id[0] == bi) {        // unique winner pops its head
      #pragma unroll
      for (int i = 0; i < TOPK-1; ++i) { v[i] = v[i+1]; id[i] = id[i+1]; }
      v[TOPK-1] = -1.f; id[TOPK-1] = 0x7fffffff;
    }
    if (lane == 0) { pv[r] = bv; pi[r] = bi; }
  }
}

// ---------------------------------------------------------------------------
// K2: per-(b,m) merge of 8x13 = 104 candidates -> global top-13, then
// mask_in_gts check + claim-bit atomicOr. One wave per (b,m).
// ---------------------------------------------------------------------------
__global__ __launch_bounds__(64) void k_topk_p2(
    const float* __restrict__ pvals, const int* __restrict__ pidx,
    const float* __restrict__ anchors, const float* __restrict__ gt_bbox,
    const float* __restrict__ mask_gt, unsigned int* __restrict__ claim)
{
  const int m = blockIdx.x, b = blockIdx.y;
  if (mask_gt[b*MM + m] <= 0.f) return;
  const int lane = threadIdx.x;
  const float* pv = pvals + ((size_t)(b*MM + m)) * NCH * TOPK;
  const int*   pi = pidx  + ((size_t)(b*MM + m)) * NCH * TOPK;
  const int NC = NCH * TOPK;   // 104

  // 2 static slots per lane (rule #20: never dynamic-index these)
  float v0=-1.f, v1=-1.f;
  int   i0=0x7fffffff, i1=0x7fffffff;
  { int j;
    j = lane;        if (j < NC) { v0 = pv[j]; i0 = pi[j]; }
    j = lane + 64;   if (j < NC) { v1 = pv[j]; i1 = pi[j]; }
  }

  const float4 gb = reinterpret_cast<const float4*>(gt_bbox)[b*MM + m];
  const unsigned int bit = 1u << m;

  for (int r = 0; r < TOPK; ++r) {
    float bv = v0; int bi = i0; int bs = 0;
    if (v1 > bv || (v1 == bv && i1 < bi)) { bv = v1; bi = i1; bs = 1; }
    const float myv = bv; const int myi = bi;
    #pragma unroll
    for (int off = 32; off; off >>= 1) {
      const float ovv = __shfl_xor(bv, off);
      const int   oii = __shfl_xor(bi, off);
      if (ovv > bv || (ovv == bv && oii < bi)) { bv = ovv; bi = oii; }
    }
    if (myv == bv && myi == bi) {           // winner lane clears its slot
      if (bs == 0) { v0 = -1.f; i0 = 0x7fffffff; }
      else         { v1 = -1.f; i1 = 0x7fffffff; }
    }
    if (lane == 0 && bi < AA) {
      const float2 xy = reinterpret_cast<const float2*>(anchors)[bi];
      const float mind = fminf(fminf(xy.x - gb.x, xy.y - gb.y),
                               fminf(gb.z - xy.x, gb.w - xy.y));
      if (mind > 1e-9f) atomicOr(&claim[b*AA + bi], bit);
    }
  }
}

// ---------------------------------------------------------------------------
// K3: per-anchor resolution with sparse CIoU recompute. fg==1 -> claiming m;
// fg>1 -> first-max argmax_m of masked overlaps (recomputed). Writes
// target_bbox + fg_mask + anchor_m/al; atomicMax pos_align/pos_ovl.
// ---------------------------------------------------------------------------
__global__ __launch_bounds__(256) void k_resolve(
    const float* __restrict__ pred_cls, const float* __restrict__ pred_bbox,
    const float* __restrict__ anchors, const int* __restrict__ gt_cls,
    const float* __restrict__ gt_bbox, const float* __restrict__ mask_gt,
    const unsigned int* __restrict__ claim,
    float* __restrict__ out_bbox, float* __restrict__ out_fg,
    int* __restrict__ anchor_m, float* __restrict__ anchor_al,
    unsigned int* __restrict__ pos_align, unsigned int* __restrict__ pos_ovl)
{
  const int b = blockIdx.y;
  __shared__ float s_x1[MM], s_y1[MM], s_x2[MM], s_y2[MM], s_at[MM], s_mgt[MM];
  __shared__ int s_lbl[MM];
  if (threadIdx.x < MM) {
    int m = threadIdx.x;
    float4 g = reinterpret_cast<const float4*>(gt_bbox)[b*MM + m];
    s_x1[m] = g.x; s_y1[m] = g.y; s_x2[m] = g.z; s_y2[m] = g.w;
    s_at[m] = atanf((g.z - g.x) / (g.w - g.y + 1e-7f));
    s_lbl[m] = gt_cls[b*MM + m];
    s_mgt[m] = mask_gt[b*MM + m];
  }
  __syncthreads();
  const int a = blockIdx.x*256 + threadIdx.x;
  if (a >= AA) return;
  const unsigned int cb = claim[b*AA + a];
  const int fg = __popc(cb);
  int asg = -1; float bestov = 0.f;
  if (fg > 0) {
    const float4 pb = reinterpret_cast<const float4*>(pred_bbox)[b*AA + a];
    const float2 xy = reinterpret_cast<const float2*>(anchors)[a];
    const float w2 = pb.z - pb.x, h2 = pb.w - pb.y + 1e-7f;
    const float at2 = atanf(w2 / h2);
    if (fg == 1) {
      asg = __ffs(cb) - 1;   // claimed => in-gts && mask_gt>0 already hold
      bestov = ciou_clip(s_x1[asg], s_y1[asg], s_x2[asg], s_y2[asg], s_at[asg],
                         pb, w2, h2, at2);
    } else {
      // is_max: first argmax over ALL m of masked overlaps
      float best = -1.f; int bm = 0;
      for (int m = 0; m < MM; ++m) {
        float ov = 0.f;
        const float mind = fminf(fminf(xy.x - s_x1[m], xy.y - s_y1[m]),
                                 fminf(s_x2[m] - xy.x, s_y2[m] - xy.y));
        if (mind > 1e-9f && s_mgt[m] > 0.f)
          ov = ciou_clip(s_x1[m], s_y1[m], s_x2[m], s_y2[m], s_at[m],
                         pb, w2, h2, at2);
        if (ov > best) { best = ov; bm = m; }   // strict > => first max
      }
      asg = bm; bestov = best;
    }
  }
  const int tgt = (asg >= 0) ? asg : 0;   // argmax of all-zero column = 0
  float4 tb; tb.x = s_x1[tgt]; tb.y = s_y1[tgt]; tb.z = s_x2[tgt]; tb.w = s_y2[tgt];
  reinterpret_cast<float4*>(out_bbox)[b*AA + a] = tb;
  out_fg[b*AA + a] = (asg >= 0) ? 1.f : 0.f;
  anchor_m[b*AA + a] = asg;
  float av = 0.f;
  if (asg >= 0) {
    const float o2 = bestov * bestov;
    av = pred_cls[(size_t)(b*AA + a)*CC + s_lbl[asg]] * (o2 * o2 * o2);
    atomicMax(&pos_align[b*MM + asg], __float_as_uint(av));    // >=0 floats
    atomicMax(&pos_ovl[b*MM + asg], __float_as_uint(bestov));
  }
  anchor_al[b*AA + a] = av;
}

// ---------------------------------------------------------------------------
// K4: target_cls (B,A,C) float4-coalesced: norm at the label slot, else 0.
// ---------------------------------------------------------------------------
__global__ __launch_bounds__(256) void k_cls(
    const int* __restrict__ anchor_m, const float* __restrict__ anchor_al,
    const unsigned int* __restrict__ pos_align, const unsigned int* __restrict__ pos_ovl,
    const int* __restrict__ gt_cls, float* __restrict__ out_cls)
{
  const int tid = blockIdx.x*256 + threadIdx.x;
  if (tid >= BB*AA*(CC/4)) return;
  const int q  = tid % (CC/4);
  const int ba = tid / (CC/4);
  const int b  = ba / AA;
  const int m  = anchor_m[ba];
  float4 o = make_float4(0.f, 0.f, 0.f, 0.f);
  if (m >= 0) {
    const float pa = __uint_as_float(pos_align[b*MM + m]);
    const float po = __uint_as_float(pos_ovl[b*MM + m]);
    const float norm = anchor_al[ba] * po / (pa + 1e-9f);
    const int lbl = gt_cls[b*MM + m];
    const int c0 = q * 4;
    if (lbl == c0    ) o.x = norm;
    if (lbl == c0 + 1) o.y = norm;
    if (lbl == c0 + 2) o.z = norm;
    if (lbl == c0 + 3) o.w = norm;
  }
  reinterpret_cast<float4*>(out_cls)[tid] = o;
}

// ---------------------------------------------------------------------------
extern "C" void kernel_launch(void* const* d_in, const int* in_sizes, int n_in,
                              void* d_out, int out_size, void* d_ws, size_t ws_size,
                              hipStream_t stream)
{
  const float* pred_cls  = (const float*)d_in[0];
  const float* pred_bbox = (const float*)d_in[1];
  const float* anchors   = (const float*)d_in[2];
  const int*   gt_cls    = (const int*)  d_in[3];
  const float* gt_bbox   = (const float*)d_in[4];
  const float* mask_gt   = (const float*)d_in[5];

  // ws layout:
  //   claim      : B*A u32          @ 0          (537600 B)
  //   pos_align  : B*M u32(float)   @ 537600     (2048 B)
  //   pos_ovl    : B*M u32(float)   @ 539648     (2048 B)
  //   anchor_m   : B*A i32          @ 541696     (537600 B)
  //   anchor_al  : B*A f32          @ 1079296    (537600 B)
  //   pvals      : B*M*NCH*13 f32   @ 1616896    (212992 B)
  //   pidx       : B*M*NCH*13 i32   @ 1829888    (212992 B)
  // total 2042880 B (~2.0 MB)
  char* ws = (char*)d_ws;
  unsigned int* claim     = (unsigned int*)(ws);
  unsigned int* pos_align = (unsigned int*)(ws + 537600);
  unsigned int* pos_ovl   = (unsigned int*)(ws + 539648);
  int*   anchor_m  = (int*)  (ws + 541696);
  float* anchor_al = (float*)(ws + 1079296);
  float* pvals     = (float*)(ws + 1616896);
  int*   pidx      = (int*)  (ws + 1829888);

  float* out_cls  = (float*)d_out;
  float* out_bbox = out_cls + (size_t)BB*AA*CC;
  float* out_fg   = out_bbox + (size_t)BB*AA*4;

  k_fused_topk<<<dim3(NCH/WPB, MM, BB), 256, 0, stream>>>(
      pred_cls, pred_bbox, anchors, gt_cls, gt_bbox, mask_gt,
      pvals, pidx, claim, pos_align, pos_ovl);
  k_topk_p2<<<dim3(MM, BB), 64, 0, stream>>>(
      pvals, pidx, anchors, gt_bbox, mask_gt, claim);
  k_resolve<<<dim3((AA + 255)/256, BB), 256, 0, stream>>>(
      pred_cls, pred_bbox, anchors, gt_cls, gt_bbox, mask_gt, claim,
      out_bbox, out_fg, anchor_m, anchor_al, pos_align, pos_ovl);
  k_cls<<<(BB*AA*(CC/4) + 255)/256, 256, 0, stream>>>(
      anchor_m, anchor_al, pos_align, pos_ovl, gt_cls, out_cls);
}

// Round 7
// 57.336 us; speedup vs baseline: 1.5465x; 1.3204x over previous
//
#include <hip/hip_runtime.h>
#include <cstdint>
#include <cstddef>

#define BB 16
#define AA 8400
#define CC 80
#define MM 32
#define TOPK 13
#define NCH 8
#define CHSZ (AA / NCH)   // 1050
#define WPB 4             // waves (chunks) per 256-thread block
#define CAP 320           // candidate capacity per (b,m,chunk)

// Shared CIoU (clipped) so every use site has the identical formula.
__device__ __forceinline__ float ciou_clip(
    float gx1, float gy1, float gx2, float gy2, float at1,
    float4 pb, float w2, float h2, float at2)
{
  const float w1 = gx2 - gx1, h1 = gy2 - gy1 + 1e-7f;
  const float iw = fmaxf(fminf(gx2, pb.z) - fmaxf(gx1, pb.x), 0.f);
  const float ih = fmaxf(fminf(gy2, pb.w) - fmaxf(gy1, pb.y), 0.f);
  const float inter = iw * ih;
  const float uni = w1*h1 + w2*h2 - inter + 1e-7f;
  const float iou = inter / uni;
  const float cw = fmaxf(gx2, pb.z) - fminf(gx1, pb.x);
  const float ch = fmaxf(gy2, pb.w) - fminf(gy1, pb.y);
  const float c2 = cw*cw + ch*ch + 1e-7f;
  const float rx = pb.x + pb.z - gx1 - gx2;
  const float ry = pb.y + pb.w - gy1 - gy2;
  const float rho2 = (rx*rx + ry*ry) * 0.25f;
  const float dv = at2 - at1;
  const float v = 0.4052847345693511f * dv * dv;
  const float alpha = v / (v - iou + (1.f + 1e-7f));
  return fmaxf(iou - (rho2 / c2 + v * alpha), 0.f);
}

// ---------------------------------------------------------------------------
// K1: scan/compact/dense-evaluate candidate generation.
// Block = (chunk-quad, m, b); each WAVE owns one 1050-anchor chunk.
//  - scan: mind-test only (anchors+gt regs), ballot-compact passing -> LDS q
//  - dense: full CIoU+score for queue entries, append val>0 to global region
//  - chunk 0: first 64 anchors evaluated fully & always written (exact
//    zero-tie candidates: if a row has <13 positives, the reference's
//    zero-fill indices provably lie in [0,64))
// No atomics: per-chunk regions + count headers (written unconditionally).
// ---------------------------------------------------------------------------
__global__ __launch_bounds__(256) void k_fused_topk(
    const float* __restrict__ pred_cls, const float* __restrict__ pred_bbox,
    const float* __restrict__ anchors, const int* __restrict__ gt_cls,
    const float* __restrict__ gt_bbox, const float* __restrict__ mask_gt,
    unsigned int* __restrict__ cnts, uint2* __restrict__ entries,
    unsigned int* __restrict__ claim,
    unsigned int* __restrict__ pos_align, unsigned int* __restrict__ pos_ovl)
{
  const int wave = threadIdx.x >> 6;     // 0..3
  const int lane = threadIdx.x & 63;
  const int chq  = blockIdx.x;           // 0..NCH/WPB-1
  const int m = blockIdx.y, b = blockIdx.z;
  const int ch = chq*WPB + wave;

  __shared__ unsigned short q[WPB][CHSZ];   // 8400 B, per-wave regions

  if (m == 0) {                          // zero-init duty (replaces memset)
    const int base = b*AA + chq*(WPB*CHSZ);
    for (int i = threadIdx.x; i < WPB*CHSZ; i += 256) claim[base + i] = 0u;
    if (chq == 0 && threadIdx.x < MM) {
      pos_align[b*MM + threadIdx.x] = 0u;
      pos_ovl[b*MM + threadIdx.x]   = 0u;
    }
  }
  if (mask_gt[b*MM + m] <= 0.f) return;  // masked gt: contributes nothing

  const float4 gb = reinterpret_cast<const float4*>(gt_bbox)[b*MM + m];
  const float at1 = atanf((gb.z - gb.x) / (gb.w - gb.y + 1e-7f));
  const int lbl = gt_cls[b*MM + m];
  const float*  clsbase = pred_cls + (size_t)b*AA*CC;
  const float4* pbase   = reinterpret_cast<const float4*>(pred_bbox) + (size_t)b*AA;
  const float2* axy     = reinterpret_cast<const float2*>(anchors);

  const int a0 = ch * CHSZ;
  uint2* ent = entries + ((size_t)((b*MM + m)*NCH + ch)) * CAP;
  int cnt = 0;
  int s_begin = 0;

  if (ch == 0) {
    // exact full eval of anchors [0,64): always-written candidates (val>=0)
    const int a = lane;
    const float2 xy = axy[a];
    const float mind = fminf(fminf(xy.x - gb.x, xy.y - gb.y),
                             fminf(gb.z - xy.x, gb.w - xy.y));
    float val = 0.f;
    if (mind > 1e-9f) {
      const float4 pb = pbase[a];
      const float w2 = pb.z - pb.x, h2 = pb.w - pb.y + 1e-7f;
      const float at2 = atanf(w2 / h2);
      const float ov = ciou_clip(gb.x, gb.y, gb.z, gb.w, at1, pb, w2, h2, at2);
      const float o2 = ov * ov;
      val = clsbase[(size_t)a*CC + lbl] * (o2 * o2 * o2);
    }
    ent[lane] = make_uint2(__float_as_uint(val), (unsigned)a);
    cnt = 64;
    s_begin = 1;
  }

  // ---- scan phase: mind-test only, compact passing into per-wave LDS q ----
  int qc = 0;
  for (int s = s_begin; s < 17; ++s) {
    const int a = a0 + s*64 + lane;
    bool pass = false;
    if (a < a0 + CHSZ) {
      const float2 xy = axy[a];
      const float mind = fminf(fminf(xy.x - gb.x, xy.y - gb.y),
                               fminf(gb.z - xy.x, gb.w - xy.y));
      pass = mind > 1e-9f;
    }
    const unsigned long long bal = __ballot(pass);
    if (pass) {
      const int pos = __popcll(bal & ((1ull << lane) - 1ull));
      q[wave][qc + pos] = (unsigned short)(a - a0);
    }
    qc += (int)__popcll(bal);
  }

  // ---- dense phase: full eval of queue, append val>0 (order-preserving) ---
  for (int k0 = 0; k0 < qc; k0 += 64) {
    const int k = k0 + lane;
    float val = 0.f; int a = 0;
    if (k < qc) {
      a = a0 + (int)q[wave][k];
      const float4 pb = pbase[a];
      const float w2 = pb.z - pb.x, h2 = pb.w - pb.y + 1e-7f;
      const float at2 = atanf(w2 / h2);
      const float ov = ciou_clip(gb.x, gb.y, gb.z, gb.w, at1, pb, w2, h2, at2);
      const float o2 = ov * ov;
      val = clsbase[(size_t)a*CC + lbl] * (o2 * o2 * o2);
    }
    const bool keep = (k < qc) && (val > 0.f);
    const unsigned long long bal = __ballot(keep);
    if (keep) {
      const int pos = cnt + (int)__popcll(bal & ((1ull << lane) - 1ull));
      if (pos < CAP) ent[pos] = make_uint2(__float_as_uint(val), (unsigned)a);
    }
    cnt += (int)__popcll(bal);
  }
  if (cnt > CAP) cnt = CAP;   // statistically unreachable; memory safety
  if (lane == 0) cnts[(b*MM + m)*NCH + ch] = (unsigned)cnt;
}

// ---------------------------------------------------------------------------
// K2: per-(b,m) merge of all chunk candidates -> global top-13 (val desc,
// idx asc), then mask_in_gts check + claim-bit atomicOr. One wave per (b,m).
// Per-lane reads are ascending-index so the equal-loses insertion is exact.
// ---------------------------------------------------------------------------
__global__ __launch_bounds__(64) void k_topk_p2(
    const unsigned int* __restrict__ cnts, const uint2* __restrict__ entries,
    const float* __restrict__ anchors, const float* __restrict__ gt_bbox,
    const float* __restrict__ mask_gt, unsigned int* __restrict__ claim)
{
  const int m = blockIdx.x, b = blockIdx.y;
  if (mask_gt[b*MM + m] <= 0.f) return;
  const int lane = threadIdx.x;
  const int row = (b*MM + m)*NCH;

  float v[TOPK]; int id[TOPK];
  #pragma unroll
  for (int i = 0; i < TOPK; ++i) { v[i] = -1.f; id[i] = 0x7fffffff; }

  for (int ch = 0; ch < NCH; ++ch) {
    const int n = (int)cnts[row + ch];
    const uint2* e = entries + (size_t)(row + ch)*CAP;
    for (int k = lane; k < n; k += 64) {
      const uint2 c = e[k];
      const float val = __uint_as_float(c.x);
      const int a = (int)c.y;
      if (val > v[TOPK-1]) {    // equal loses (ascending idx order) -> exact
        #pragma unroll
        for (int i = TOPK-1; i >= 1; --i) {   // static-index shift network
          const bool ci = val > v[i];
          const bool cp = val > v[i-1];
          if (ci) {
            if (cp) { v[i] = v[i-1]; id[i] = id[i-1]; }
            else    { v[i] = val;    id[i] = a; }
          }
        }
        if (val > v[0]) { v[0] = val; id[0] = a; }
      }
    }
  }

  const float4 gb = reinterpret_cast<const float4*>(gt_bbox)[b*MM + m];
  const unsigned int bit = 1u << m;

  for (int r = 0; r < TOPK; ++r) {
    float bv = v[0]; int bi = id[0];
    #pragma unroll
    for (int off = 32; off; off >>= 1) {
      const float ovv = __shfl_xor(bv, off);
      const int   oii = __shfl_xor(bi, off);
      if (ovv > bv || (ovv == bv && oii < bi)) { bv = ovv; bi = oii; }
    }
    if (v[0] == bv && id[0] == bi) {        // unique winner pops its head
      #pragma unroll
      for (int i = 0; i < TOPK-1; ++i) { v[i] = v[i+1]; id[i] = id[i+1]; }
      v[TOPK-1] = -1.f; id[TOPK-1] = 0x7fffffff;
    }
    if (lane == 0 && bi < AA) {
      const float2 xy = reinterpret_cast<const float2*>(anchors)[bi];
      const float mind = fminf(fminf(xy.x - gb.x, xy.y - gb.y),
                               fminf(gb.z - xy.x, gb.w - xy.y));
      if (mind > 1e-9f) atomicOr(&claim[b*AA + bi], bit);
    }
  }
}

// ---------------------------------------------------------------------------
// K3: per-anchor resolution with sparse CIoU recompute. fg==1 -> claiming m;
// fg>1 -> first-max argmax_m of masked overlaps (recomputed). Writes
// target_bbox + fg_mask + anchor_m/al; atomicMax pos_align/pos_ovl.
// ---------------------------------------------------------------------------
__global__ __launch_bounds__(256) void k_resolve(
    const float* __restrict__ pred_cls, const float* __restrict__ pred_bbox,
    const float* __restrict__ anchors, const int* __restrict__ gt_cls,
    const float* __restrict__ gt_bbox, const float* __restrict__ mask_gt,
    const unsigned int* __restrict__ claim,
    float* __restrict__ out_bbox, float* __restrict__ out_fg,
    int* __restrict__ anchor_m, float* __restrict__ anchor_al,
    unsigned int* __restrict__ pos_align, unsigned int* __restrict__ pos_ovl)
{
  const int b = blockIdx.y;
  __shared__ float s_x1[MM], s_y1[MM], s_x2[MM], s_y2[MM], s_at[MM], s_mgt[MM];
  __shared__ int s_lbl[MM];
  if (threadIdx.x < MM) {
    int m = threadIdx.x;
    float4 g = reinterpret_cast<const float4*>(gt_bbox)[b*MM + m];
    s_x1[m] = g.x; s_y1[m] = g.y; s_x2[m] = g.z; s_y2[m] = g.w;
    s_at[m] = atanf((g.z - g.x) / (g.w - g.y + 1e-7f));
    s_lbl[m] = gt_cls[b*MM + m];
    s_mgt[m] = mask_gt[b*MM + m];
  }
  __syncthreads();
  const int a = blockIdx.x*256 + threadIdx.x;
  if (a >= AA) return;
  const unsigned int cb = claim[b*AA + a];
  const int fg = __popc(cb);
  int asg = -1; float bestov = 0.f;
  if (fg > 0) {
    const float4 pb = reinterpret_cast<const float4*>(pred_bbox)[b*AA + a];
    const float2 xy = reinterpret_cast<const float2*>(anchors)[a];
    const float w2 = pb.z - pb.x, h2 = pb.w - pb.y + 1e-7f;
    const float at2 = atanf(w2 / h2);
    if (fg == 1) {
      asg = __ffs(cb) - 1;   // claimed => in-gts && mask_gt>0 already hold
      bestov = ciou_clip(s_x1[asg], s_y1[asg], s_x2[asg], s_y2[asg], s_at[asg],
                         pb, w2, h2, at2);
    } else {
      // is_max: first argmax over ALL m of masked overlaps
      float best = -1.f; int bm = 0;
      for (int m = 0; m < MM; ++m) {
        float ov = 0.f;
        const float mind = fminf(fminf(xy.x - s_x1[m], xy.y - s_y1[m]),
                                 fminf(s_x2[m] - xy.x, s_y2[m] - xy.y));
        if (mind > 1e-9f && s_mgt[m] > 0.f)
          ov = ciou_clip(s_x1[m], s_y1[m], s_x2[m], s_y2[m], s_at[m],
                         pb, w2, h2, at2);
        if (ov > best) { best = ov; bm = m; }   // strict > => first max
      }
      asg = bm; bestov = best;
    }
  }
  const int tgt = (asg >= 0) ? asg : 0;   // argmax of all-zero column = 0
  float4 tb; tb.x = s_x1[tgt]; tb.y = s_y1[tgt]; tb.z = s_x2[tgt]; tb.w = s_y2[tgt];
  reinterpret_cast<float4*>(out_bbox)[b*AA + a] = tb;
  out_fg[b*AA + a] = (asg >= 0) ? 1.f : 0.f;
  anchor_m[b*AA + a] = asg;
  float av = 0.f;
  if (asg >= 0) {
    const float o2 = bestov * bestov;
    av = pred_cls[(size_t)(b*AA + a)*CC + s_lbl[asg]] * (o2 * o2 * o2);
    atomicMax(&pos_align[b*MM + asg], __float_as_uint(av));    // >=0 floats
    atomicMax(&pos_ovl[b*MM + asg], __float_as_uint(bestov));
  }
  anchor_al[b*AA + a] = av;
}

// ---------------------------------------------------------------------------
// K4: target_cls (B,A,C) float4-coalesced: norm at the label slot, else 0.
// ---------------------------------------------------------------------------
__global__ __launch_bounds__(256) void k_cls(
    const int* __restrict__ anchor_m, const float* __restrict__ anchor_al,
    const unsigned int* __restrict__ pos_align, const unsigned int* __restrict__ pos_ovl,
    const int* __restrict__ gt_cls, float* __restrict__ out_cls)
{
  const int tid = blockIdx.x*256 + threadIdx.x;
  if (tid >= BB*AA*(CC/4)) return;
  const int q  = tid % (CC/4);
  const int ba = tid / (CC/4);
  const int b  = ba / AA;
  const int m  = anchor_m[ba];
  float4 o = make_float4(0.f, 0.f, 0.f, 0.f);
  if (m >= 0) {
    const float pa = __uint_as_float(pos_align[b*MM + m]);
    const float po = __uint_as_float(pos_ovl[b*MM + m]);
    const float norm = anchor_al[ba] * po / (pa + 1e-9f);
    const int lbl = gt_cls[b*MM + m];
    const int c0 = q * 4;
    if (lbl == c0    ) o.x = norm;
    if (lbl == c0 + 1) o.y = norm;
    if (lbl == c0 + 2) o.z = norm;
    if (lbl == c0 + 3) o.w = norm;
  }
  reinterpret_cast<float4*>(out_cls)[tid] = o;
}

// ---------------------------------------------------------------------------
extern "C" void kernel_launch(void* const* d_in, const int* in_sizes, int n_in,
                              void* d_out, int out_size, void* d_ws, size_t ws_size,
                              hipStream_t stream)
{
  const float* pred_cls  = (const float*)d_in[0];
  const float* pred_bbox = (const float*)d_in[1];
  const float* anchors   = (const float*)d_in[2];
  const int*   gt_cls    = (const int*)  d_in[3];
  const float* gt_bbox   = (const float*)d_in[4];
  const float* mask_gt   = (const float*)d_in[5];

  // ws layout:
  //   claim      : B*A u32             @ 0          (537600 B)
  //   pos_align  : B*M u32(float)      @ 537600     (2048 B)
  //   pos_ovl    : B*M u32(float)      @ 539648     (2048 B)
  //   anchor_m   : B*A i32             @ 541696     (537600 B)
  //   anchor_al  : B*A f32             @ 1079296    (537600 B)
  //   cnts       : B*M*NCH u32         @ 1616896    (16384 B)
  //   entries    : B*M*NCH*CAP uint2   @ 1633280    (10485760 B)
  // total 12119040 B (~11.6 MB)
  char* ws = (char*)d_ws;
  unsigned int* claim     = (unsigned int*)(ws);
  unsigned int* pos_align = (unsigned int*)(ws + 537600);
  unsigned int* pos_ovl   = (unsigned int*)(ws + 539648);
  int*   anchor_m  = (int*)  (ws + 541696);
  float* anchor_al = (float*)(ws + 1079296);
  unsigned int* cnts = (unsigned int*)(ws + 1616896);
  uint2* entries     = (uint2*)(ws + 1633280);

  float* out_cls  = (float*)d_out;
  float* out_bbox = out_cls + (size_t)BB*AA*CC;
  float* out_fg   = out_bbox + (size_t)BB*AA*4;

  k_fused_topk<<<dim3(NCH/WPB, MM, BB), 256, 0, stream>>>(
      pred_cls, pred_bbox, anchors, gt_cls, gt_bbox, mask_gt,
      cnts, entries, claim, pos_align, pos_ovl);
  k_topk_p2<<<dim3(MM, BB), 64, 0, stream>>>(
      cnts, entries, anchors, gt_bbox, mask_gt, claim);
  k_resolve<<<dim3((AA + 255)/256, BB), 256, 0, stream>>>(
      pred_cls, pred_bbox, anchors, gt_cls, gt_bbox, mask_gt, claim,
      out_bbox, out_fg, anchor_m, anchor_al, pos_align, pos_ovl);
  k_cls<<<(BB*AA*(CC/4) + 255)/256, 256, 0, stream>>>(
      anchor_m, anchor_al, pos_align, pos_ovl, gt_cls, out_cls);
}